// Round 9
// baseline (345.801 us; speedup 1.0000x reference)
//
#include <hip/hip_runtime.h>
#include <stdint.h>

#define BB 4
#define CC 64
#define HH 192
#define WW 192
#define HWN (HH*WW)            // 36864
#define KH 4
#define KW 16
#define PW (WW/KW)             // 12
#define MP ((HH/KH)*(WW/KW))   // 576
#define MITER (MP/64)          // 9
#define SCALE_W 65536.0f
#define INV_SCALE (1.0f/65536.0f)

typedef _Float16 half8 __attribute__((ext_vector_type(8)));
typedef _Float16 half4 __attribute__((ext_vector_type(4)));
typedef float floatx4 __attribute__((ext_vector_type(4)));

// async global->LDS, 16B per lane; LDS dest = uniform base + lane*16 (HW rule)
static __device__ __forceinline__ void gload16(const void* g, void* l) {
  __builtin_amdgcn_global_load_lds((const __attribute__((address_space(1))) void*)g,
                                   (__attribute__((address_space(3))) void*)l, 16, 0, 0);
}
#define WAITCNT_VM(N) asm volatile("s_waitcnt vmcnt(" #N ")" ::: "memory")
#define WAITCNT_LGKM0 asm volatile("s_waitcnt lgkmcnt(0)" ::: "memory")

// ---------------- pooling: kptF (f16 frag-order) and Vp (f32, [b][c][m]) ---
__global__ __launch_bounds__(256) void pool_kernel(
    const float* __restrict__ Kin, const float* __restrict__ Vin,
    _Float16* __restrict__ kptF, float* __restrict__ vp) {
  int t = blockIdx.x * 256 + threadIdx.x;
  const int total = BB * CC * MP;
  bool isV = t >= total;
  int idx = isV ? t - total : t;
  int m = idx % MP;
  int c = (idx / MP) % CC;
  int b = idx / (MP * CC);
  int mh = m / PW, mw = m % PW;
  const float* src = (isV ? Vin : Kin) + (((b * CC + c) * HH + mh * KH) * WW + mw * KW);
  float s = 0.f;
#pragma unroll
  for (int r = 0; r < KH; ++r) {
    const float4* row = (const float4*)(src + r * WW);
#pragma unroll
    for (int j = 0; j < KW / 4; ++j) {
      float4 v = row[j];
      s += v.x + v.y + v.z + v.w;
    }
  }
  s *= (1.0f / (KH * KW));
  if (isV) {
    vp[(b * CC + c) * MP + m] = s;
  } else {
    int mi = m >> 6, mloc = m & 63, l15 = mloc >> 2, mf = mloc & 3;
    int ks = c >> 5, lhi = (c >> 3) & 3, e = c & 7;
    int lane = lhi * 16 + l15;
    kptF[(((((b * MITER + mi) * 4 + mf) * 2 + ks)) * 64 + lane) * 8 + e] = (_Float16)s;
  }
}

// ---------------- pass A: colsum (REAL, unchanged from R8) -----------------
__global__ __launch_bounds__(512) void colsum_kernel(
    const float* __restrict__ Q, const _Float16* __restrict__ kptF,
    float* __restrict__ colsum) {
  __shared__ float cs[MP];
  __shared__ char stg[MITER * 8 * 1024];  // 72KB
  int b = blockIdx.y;
  int n0 = blockIdx.x * 256;
  int tid = threadIdx.x;
  int wv = tid >> 6;
  int lane = tid & 63;
  int l15 = lane & 15, lhi = lane >> 4;

  for (int i = tid; i < MP; i += 512) cs[i] = 0.f;

  const _Float16* kb = kptF + b * MITER * 8 * 512;
#pragma unroll
  for (int j = 0; j < 9; ++j) {
    int q = wv * 9 + j;
    gload16(kb + q * 512 + lane * 8, stg + q * 1024);
  }

  const float* Qb = Q + b * CC * HWN;
  int nrow = n0 + wv * 32 + l15;
  half8 afrag[2][2];
#pragma unroll
  for (int nf = 0; nf < 2; ++nf)
#pragma unroll
    for (int ks = 0; ks < 2; ++ks)
#pragma unroll
      for (int e = 0; e < 8; ++e)
        afrag[nf][ks][e] = (_Float16)Qb[(ks * 32 + lhi * 8 + e) * HWN + nrow + nf * 16];

  __syncthreads();

  floatx4 zero = {0.f, 0.f, 0.f, 0.f};
#pragma unroll
  for (int mi = 0; mi < MITER; ++mi) {
    half8 bfr[4][2];
#pragma unroll
    for (int mf = 0; mf < 4; ++mf)
#pragma unroll
      for (int ks = 0; ks < 2; ++ks)
        bfr[mf][ks] = *(const half8*)(stg + ((mi * 4 + mf) * 2 + ks) * 1024 + lane * 16);
    floatx4 sacc[2][4];
#pragma unroll
    for (int nf = 0; nf < 2; ++nf)
#pragma unroll
      for (int mf = 0; mf < 4; ++mf) sacc[nf][mf] = zero;
    __builtin_amdgcn_s_setprio(1);
#pragma unroll
    for (int ks = 0; ks < 2; ++ks)
#pragma unroll
      for (int nf = 0; nf < 2; ++nf)
#pragma unroll
        for (int mf = 0; mf < 4; ++mf)
          sacc[nf][mf] = __builtin_amdgcn_mfma_f32_16x16x32_f16(
              afrag[nf][ks], bfr[mf][ks], sacc[nf][mf], 0, 0, 0);
    __builtin_amdgcn_s_setprio(0);
#pragma unroll
    for (int mf = 0; mf < 4; ++mf) {
      float s = 0.f;
#pragma unroll
      for (int nf = 0; nf < 2; ++nf)
#pragma unroll
        for (int r = 0; r < 4; ++r)
          s += __expf(sacc[nf][mf][r]);
      s += __shfl_xor(s, 16);
      s += __shfl_xor(s, 32);
      if (lane < 16) atomicAdd(&cs[mi * 64 + l15 * 4 + mf], s);
    }
  }
  __syncthreads();
  for (int i = tid; i < MP; i += 512) atomicAdd(&colsum[b * MP + i], cs[i]);
}

// ---------------- W' = Vp/colsum * 2^16 (f16, frag-order) ------------------
__global__ __launch_bounds__(256) void wprep_kernel(
    const float* __restrict__ vp, const float* __restrict__ colsum,
    _Float16* __restrict__ wqF) {
  int t = blockIdx.x * 256 + threadIdx.x;
  int m = t % MP;
  int c = (t / MP) % CC;
  int b = t / (CC * MP);
  float w = vp[t] / colsum[b * MP + m] * SCALE_W;
  int cf = c >> 4, l15 = c & 15;
  int mi = m >> 6, mloc = m & 63;
  int ks = mloc >> 5, lhi = (mloc >> 3) & 3, e = mloc & 7;
  int lane = lhi * 16 + l15;
  wqF[((((b * MITER + mi) * 4 + cf) * 2 + ks) * 64 + lane) * 8 + e] = (_Float16)w;
}

// ---------------- pass B: attn (REAL, unchanged from R8) -------------------
__global__ __launch_bounds__(256) void attn_main_kernel(
    const float* __restrict__ Q, const _Float16* __restrict__ kptF,
    const _Float16* __restrict__ wqF, float* __restrict__ out) {
  __shared__ char lds[3 * 16384 + 4 * 4096];  // 64KB exactly
  char* stg = lds;
  int b = blockIdx.y;
  int n0 = blockIdx.x * 128;
  int tid = threadIdx.x;
  int wv = tid >> 6;
  int lane = tid & 63;
  int l15 = lane & 15, lhi = lane >> 4;
  char* eb = lds + 49152 + wv * 4096;

  const _Float16* kb = kptF + b * MITER * 8 * 512;
  const _Float16* wb = wqF + b * MITER * 8 * 512;

#define STAGE_A(tt, ss)                                                        \
  {                                                                            \
    int q0_ = wv * 4;                                                          \
    _Pragma("unroll") for (int j_ = 0; j_ < 4; ++j_) {                         \
      int q_ = q0_ + j_;                                                       \
      const _Float16* sp_ = (q_ < 8 ? kb + (tt) * 4096 + q_ * 512              \
                                    : wb + (tt) * 4096 + (q_ - 8) * 512) +     \
                            lane * 8;                                          \
      gload16(sp_, stg + (ss) * 16384 + q_ * 1024);                            \
    }                                                                          \
  }

  STAGE_A(0, 0);
  STAGE_A(1, 1);

  const float* Qb = Q + b * CC * HWN;
  int nrow = n0 + wv * 32 + l15;
  half8 afrag[2][2];
#pragma unroll
  for (int nf = 0; nf < 2; ++nf)
#pragma unroll
    for (int ks = 0; ks < 2; ++ks)
#pragma unroll
      for (int e = 0; e < 8; ++e)
        afrag[nf][ks][e] = (_Float16)Qb[(ks * 32 + lhi * 8 + e) * HWN + nrow + nf * 16];

  floatx4 zero = {0.f, 0.f, 0.f, 0.f};
  floatx4 oacc[4][2];
#pragma unroll
  for (int cf = 0; cf < 4; ++cf)
#pragma unroll
    for (int nf = 0; nf < 2; ++nf) oacc[cf][nf] = zero;

  WAITCNT_VM(4);
  __builtin_amdgcn_sched_barrier(0);
  __builtin_amdgcn_s_barrier();

#pragma unroll
  for (int mi = 0; mi < MITER; ++mi) {
    const int sc = mi % 3;
    const int spv = (mi + 2) % 3;

    if (mi >= 1) {
      if (mi <= 7) { WAITCNT_VM(4); } else { WAITCNT_VM(0); }
      __builtin_amdgcn_sched_barrier(0);
      __builtin_amdgcn_s_barrier();
    }

    half8 bfr[4][2];
#pragma unroll
    for (int mf = 0; mf < 4; ++mf)
#pragma unroll
      for (int ks = 0; ks < 2; ++ks)
        bfr[mf][ks] = *(const half8*)(stg + sc * 16384 + (mf * 2 + ks) * 1024 + lane * 16);
    half8 wfr[4][2];
    half8 ef[2][2];
    if (mi >= 1) {
#pragma unroll
      for (int cf = 0; cf < 4; ++cf)
#pragma unroll
        for (int ks = 0; ks < 2; ++ks)
          wfr[cf][ks] = *(const half8*)(stg + spv * 16384 + 8192 + (cf * 2 + ks) * 1024 + lane * 16);
#pragma unroll
      for (int nf = 0; nf < 2; ++nf)
#pragma unroll
        for (int ks = 0; ks < 2; ++ks) {
          int nl = nf * 16 + l15;
          int slot = (ks * 4 + lhi) ^ (nl & 7);
          ef[nf][ks] = *(const half8*)(eb + nl * 128 + (slot << 4));
        }
    }

    WAITCNT_LGKM0;
    __builtin_amdgcn_sched_barrier(0);
    __builtin_amdgcn_s_barrier();

    if (mi + 2 < MITER) STAGE_A(mi + 2, spv);

    floatx4 sacc[2][4];
#pragma unroll
    for (int nf = 0; nf < 2; ++nf)
#pragma unroll
      for (int mf = 0; mf < 4; ++mf) sacc[nf][mf] = zero;
    __builtin_amdgcn_s_setprio(1);
#pragma unroll
    for (int ks = 0; ks < 2; ++ks)
#pragma unroll
      for (int nf = 0; nf < 2; ++nf)
#pragma unroll
        for (int mf = 0; mf < 4; ++mf)
          sacc[nf][mf] = __builtin_amdgcn_mfma_f32_16x16x32_f16(
              afrag[nf][ks], bfr[mf][ks], sacc[nf][mf], 0, 0, 0);
    if (mi >= 1) {
#pragma unroll
      for (int ks = 0; ks < 2; ++ks)
#pragma unroll
        for (int cf = 0; cf < 4; ++cf)
#pragma unroll
          for (int nf = 0; nf < 2; ++nf)
            oacc[cf][nf] = __builtin_amdgcn_mfma_f32_16x16x32_f16(
                wfr[cf][ks], ef[nf][ks], oacc[cf][nf], 0, 0, 0);
    }
    __builtin_amdgcn_s_setprio(0);

#pragma unroll
    for (int nf = 0; nf < 2; ++nf)
#pragma unroll
      for (int r = 0; r < 4; ++r) {
        int nl = nf * 16 + lhi * 4 + r;
        half4 h;
#pragma unroll
        for (int mf = 0; mf < 4; ++mf) h[mf] = (_Float16)__expf(sacc[nf][mf][r]);
        int byte = nl * 128 + ((((l15 >> 1) ^ (nl & 7))) << 4) + ((l15 & 1) << 3);
        *(half4*)(eb + byte) = h;
      }
  }

  {
    half8 wfr[4][2];
#pragma unroll
    for (int cf = 0; cf < 4; ++cf)
#pragma unroll
      for (int ks = 0; ks < 2; ++ks)
        wfr[cf][ks] = *(const half8*)(stg + 2 * 16384 + 8192 + (cf * 2 + ks) * 1024 + lane * 16);
    half8 ef[2][2];
#pragma unroll
    for (int nf = 0; nf < 2; ++nf)
#pragma unroll
      for (int ks = 0; ks < 2; ++ks) {
        int nl = nf * 16 + l15;
        int slot = (ks * 4 + lhi) ^ (nl & 7);
        ef[nf][ks] = *(const half8*)(eb + nl * 128 + (slot << 4));
      }
    __builtin_amdgcn_s_setprio(1);
#pragma unroll
    for (int ks = 0; ks < 2; ++ks)
#pragma unroll
      for (int cf = 0; cf < 4; ++cf)
#pragma unroll
        for (int nf = 0; nf < 2; ++nf)
          oacc[cf][nf] = __builtin_amdgcn_mfma_f32_16x16x32_f16(
              wfr[cf][ks], ef[nf][ks], oacc[cf][nf], 0, 0, 0);
    __builtin_amdgcn_s_setprio(0);
  }

  float* ob = out + b * CC * HWN;
#pragma unroll
  for (int cf = 0; cf < 4; ++cf)
#pragma unroll
    for (int nf = 0; nf < 2; ++nf)
#pragma unroll
      for (int r = 0; r < 4; ++r) {
        int c = cf * 16 + lhi * 4 + r;
        int n = n0 + wv * 32 + nf * 16 + l15;
        ob[c * HWN + n] = oacc[cf][nf][r] * INV_SCALE;
      }
}

// ================= ABLATION PROBES (write only dead ws scratch) ============
// V1: no MFMA | V2: no exp | V3: no reduce | V4: no Q gather
template<int V>
__global__ __launch_bounds__(512) void cs_probe(
    const float* __restrict__ Q, const _Float16* __restrict__ kptF,
    float* __restrict__ scratch) {
  __shared__ float cs[MP];
  __shared__ char stg[MITER * 8 * 1024];
  int b = blockIdx.y;
  int n0 = blockIdx.x * 256;
  int tid = threadIdx.x;
  int wv = tid >> 6, lane = tid & 63;
  int l15 = lane & 15, lhi = lane >> 4;
  for (int i = tid; i < MP; i += 512) cs[i] = 0.f;
  const _Float16* kb = kptF + b * MITER * 8 * 512;
#pragma unroll
  for (int j = 0; j < 9; ++j) {
    int q = wv * 9 + j;
    gload16(kb + q * 512 + lane * 8, stg + q * 1024);
  }
  float keep = 0.f;
  half8 afrag[2][2];
  if constexpr (V != 4) {
    const float* Qb = Q + b * CC * HWN;
    int nrow = n0 + wv * 32 + l15;
#pragma unroll
    for (int nf = 0; nf < 2; ++nf)
#pragma unroll
      for (int ks = 0; ks < 2; ++ks)
#pragma unroll
        for (int e = 0; e < 8; ++e)
          afrag[nf][ks][e] = (_Float16)Qb[(ks * 32 + lhi * 8 + e) * HWN + nrow + nf * 16];
  } else {
#pragma unroll
    for (int nf = 0; nf < 2; ++nf)
#pragma unroll
      for (int ks = 0; ks < 2; ++ks)
#pragma unroll
        for (int e = 0; e < 8; ++e)
          afrag[nf][ks][e] = (_Float16)1.0f;
  }
  __syncthreads();
  floatx4 zero = {0.f, 0.f, 0.f, 0.f};
#pragma unroll
  for (int mi = 0; mi < MITER; ++mi) {
    half8 bfr[4][2];
#pragma unroll
    for (int mf = 0; mf < 4; ++mf)
#pragma unroll
      for (int ks = 0; ks < 2; ++ks)
        bfr[mf][ks] = *(const half8*)(stg + ((mi * 4 + mf) * 2 + ks) * 1024 + lane * 16);
    if constexpr (V == 1) {
#pragma unroll
      for (int mf = 0; mf < 4; ++mf) {
        float s = 0.f;
#pragma unroll
        for (int ks = 0; ks < 2; ++ks)
#pragma unroll
          for (int r = 0; r < 4; ++r)
            s += __expf((float)bfr[mf][ks][r]);
        s += __shfl_xor(s, 16);
        s += __shfl_xor(s, 32);
        if (lane < 16) atomicAdd(&cs[mi * 64 + l15 * 4 + mf], s);
      }
    } else {
      floatx4 sacc[2][4];
#pragma unroll
      for (int nf = 0; nf < 2; ++nf)
#pragma unroll
        for (int mf = 0; mf < 4; ++mf) sacc[nf][mf] = zero;
      __builtin_amdgcn_s_setprio(1);
#pragma unroll
      for (int ks = 0; ks < 2; ++ks)
#pragma unroll
        for (int nf = 0; nf < 2; ++nf)
#pragma unroll
          for (int mf = 0; mf < 4; ++mf)
            sacc[nf][mf] = __builtin_amdgcn_mfma_f32_16x16x32_f16(
                afrag[nf][ks], bfr[mf][ks], sacc[nf][mf], 0, 0, 0);
      __builtin_amdgcn_s_setprio(0);
#pragma unroll
      for (int mf = 0; mf < 4; ++mf) {
        float s = 0.f;
#pragma unroll
        for (int nf = 0; nf < 2; ++nf)
#pragma unroll
          for (int r = 0; r < 4; ++r) {
            float v = sacc[nf][mf][r];
            if constexpr (V == 2) s += v;
            else if constexpr (V == 3) keep += __expf(v);
            else s += __expf(v);
          }
        if constexpr (V != 3) {
          s += __shfl_xor(s, 16);
          s += __shfl_xor(s, 32);
          if (lane < 16) atomicAdd(&cs[mi * 64 + l15 * 4 + mf], s);
        }
      }
    }
  }
  if constexpr (V == 1) keep += (float)afrag[0][0][0] + (float)afrag[1][1][7];
  __syncthreads();
  for (int i = tid; i < MP; i += 512)
    scratch[b * MP + i] = cs[i] + keep;
}

// V5: occupancy probe — same total work, 24KB LDS, 3 m-tiles/block, grid x3
__global__ __launch_bounds__(512) void cs_probe5(
    const float* __restrict__ Q, const _Float16* __restrict__ kptF,
    float* __restrict__ scratch) {
  __shared__ float cs[192];
  __shared__ char stg[3 * 8 * 1024];
  int b = blockIdx.y;
  int mz = blockIdx.z;
  int n0 = blockIdx.x * 256;
  int tid = threadIdx.x;
  int wv = tid >> 6, lane = tid & 63;
  int l15 = lane & 15, lhi = lane >> 4;
  for (int i = tid; i < 192; i += 512) cs[i] = 0.f;
  const _Float16* kb = kptF + b * MITER * 8 * 512 + mz * 3 * 8 * 512;
#pragma unroll
  for (int j = 0; j < 3; ++j) {
    int q = wv * 3 + j;
    gload16(kb + q * 512 + lane * 8, stg + q * 1024);
  }
  const float* Qb = Q + b * CC * HWN;
  int nrow = n0 + wv * 32 + l15;
  half8 afrag[2][2];
#pragma unroll
  for (int nf = 0; nf < 2; ++nf)
#pragma unroll
    for (int ks = 0; ks < 2; ++ks)
#pragma unroll
      for (int e = 0; e < 8; ++e)
        afrag[nf][ks][e] = (_Float16)Qb[(ks * 32 + lhi * 8 + e) * HWN + nrow + nf * 16];
  __syncthreads();
  floatx4 zero = {0.f, 0.f, 0.f, 0.f};
#pragma unroll
  for (int mi = 0; mi < 3; ++mi) {
    half8 bfr[4][2];
#pragma unroll
    for (int mf = 0; mf < 4; ++mf)
#pragma unroll
      for (int ks = 0; ks < 2; ++ks)
        bfr[mf][ks] = *(const half8*)(stg + ((mi * 4 + mf) * 2 + ks) * 1024 + lane * 16);
    floatx4 sacc[2][4];
#pragma unroll
    for (int nf = 0; nf < 2; ++nf)
#pragma unroll
      for (int mf = 0; mf < 4; ++mf) sacc[nf][mf] = zero;
    __builtin_amdgcn_s_setprio(1);
#pragma unroll
    for (int ks = 0; ks < 2; ++ks)
#pragma unroll
      for (int nf = 0; nf < 2; ++nf)
#pragma unroll
        for (int mf = 0; mf < 4; ++mf)
          sacc[nf][mf] = __builtin_amdgcn_mfma_f32_16x16x32_f16(
              afrag[nf][ks], bfr[mf][ks], sacc[nf][mf], 0, 0, 0);
    __builtin_amdgcn_s_setprio(0);
#pragma unroll
    for (int mf = 0; mf < 4; ++mf) {
      float s = 0.f;
#pragma unroll
      for (int nf = 0; nf < 2; ++nf)
#pragma unroll
        for (int r = 0; r < 4; ++r)
          s += __expf(sacc[nf][mf][r]);
      s += __shfl_xor(s, 16);
      s += __shfl_xor(s, 32);
      if (lane < 16) atomicAdd(&cs[mi * 64 + l15 * 4 + mf], s);
    }
  }
  __syncthreads();
  for (int i = tid; i < 192; i += 512)
    scratch[4096 + (b * 3 + mz) * 192 + i] = cs[i];
}

extern "C" void kernel_launch(void* const* d_in, const int* in_sizes, int n_in,
                              void* d_out, int out_size, void* d_ws, size_t ws_size,
                              hipStream_t stream) {
  const float* K = (const float*)d_in[0];
  const float* Q = (const float*)d_in[1];
  const float* V = (const float*)d_in[2];
  float* out = (float*)d_out;
  char* ws = (char*)d_ws;
  _Float16* kptF  = (_Float16*)(ws);                          // 294912 B
  float*    vp    = (float*)(ws + 294912);                    // 589824 B
  _Float16* wqF   = (_Float16*)(ws + 294912 + 589824);        // 294912 B
  float*    colsum = (float*)(ws + 294912 + 589824 + 294912); // 9216 B

  hipMemsetAsync(colsum, 0, BB * MP * sizeof(float), stream);
  pool_kernel<<<(2 * BB * CC * MP) / 256, 256, 0, stream>>>(K, V, kptF, vp);
  colsum_kernel<<<dim3(HWN / 256, BB), 512, 0, stream>>>(Q, kptF, colsum);
  wprep_kernel<<<(BB * CC * MP) / 256, 256, 0, stream>>>(vp, colsum, wqF);
  attn_main_kernel<<<dim3(HWN / 128, BB), 256, 0, stream>>>(Q, kptF, wqF, out);

  // ---- ablation probes (vp region is dead after wprep; outputs unused) ----
  float* probe_scr = vp;
  cs_probe<1><<<dim3(HWN / 256, BB), 512, 0, stream>>>(Q, kptF, probe_scr);
  cs_probe<2><<<dim3(HWN / 256, BB), 512, 0, stream>>>(Q, kptF, probe_scr);
  cs_probe<3><<<dim3(HWN / 256, BB), 512, 0, stream>>>(Q, kptF, probe_scr);
  cs_probe<4><<<dim3(HWN / 256, BB), 512, 0, stream>>>(Q, kptF, probe_scr);
  cs_probe5<<<dim3(HWN / 256, BB, 3), 512, 0, stream>>>(Q, kptF, probe_scr);
}

// Round 10
// 96.967 us; speedup vs baseline: 3.5662x; 3.5662x over previous
//
#include <hip/hip_runtime.h>
#include <stdint.h>

#define BB 4
#define CC 64
#define HH 192
#define WW 192
#define HWN (HH*WW)            // 36864
#define KH 4
#define KW 16
#define PW (WW/KW)             // 12
#define MP ((HH/KH)*(WW/KW))   // 576
#define MITER (MP/64)          // 9
#define SCALE_W 65536.0f
#define INV_SCALE (1.0f/65536.0f)

typedef _Float16 half8 __attribute__((ext_vector_type(8)));
typedef _Float16 half4 __attribute__((ext_vector_type(4)));
typedef float floatx4 __attribute__((ext_vector_type(4)));

// async global->LDS, 16B per lane; LDS dest = uniform base + lane*16 (HW rule)
static __device__ __forceinline__ void gload16(const void* g, void* l) {
  __builtin_amdgcn_global_load_lds((const __attribute__((address_space(1))) void*)g,
                                   (__attribute__((address_space(3))) void*)l, 16, 0, 0);
}
#define WAITCNT_VM(N) asm volatile("s_waitcnt vmcnt(" #N ")" ::: "memory")
#define WAITCNT_LGKM0 asm volatile("s_waitcnt lgkmcnt(0)" ::: "memory")

// kptF fragment order (GEMM1 B-operand, cols permuted m=l15*4+mf):
//   chunk = (mi*4+mf)*2+ks per batch; f16 idx = chunk*512 + lane*8 + e
//   value = Kp[b][m=mi*64+(lane&15)*4+mf][c=ks*32+(lane>>4)*8+e]
// wqF fragment order (GEMM2 A-operand):
//   chunk = (mi*4+cf)*2+ks ; value = W'[b][c=cf*16+(lane&15)][m=mi*64+ks*32+(lane>>4)*8+e]

// ---------------- pooling: kptF (f16 frag-order) and Vp (f32, [b][c][m]) ---
__global__ __launch_bounds__(256) void pool_kernel(
    const float* __restrict__ Kin, const float* __restrict__ Vin,
    _Float16* __restrict__ kptF, float* __restrict__ vp) {
  int t = blockIdx.x * 256 + threadIdx.x;
  const int total = BB * CC * MP;
  bool isV = t >= total;
  int idx = isV ? t - total : t;
  int m = idx % MP;
  int c = (idx / MP) % CC;
  int b = idx / (MP * CC);
  int mh = m / PW, mw = m % PW;
  const float* src = (isV ? Vin : Kin) + (((b * CC + c) * HH + mh * KH) * WW + mw * KW);
  float s = 0.f;
#pragma unroll
  for (int r = 0; r < KH; ++r) {
    const float4* row = (const float4*)(src + r * WW);
#pragma unroll
    for (int j = 0; j < KW / 4; ++j) {
      float4 v = row[j];
      s += v.x + v.y + v.z + v.w;
    }
  }
  s *= (1.0f / (KH * KW));
  if (isV) {
    vp[(b * CC + c) * MP + m] = s;
  } else {
    int mi = m >> 6, mloc = m & 63, l15 = mloc >> 2, mf = mloc & 3;
    int ks = c >> 5, lhi = (c >> 3) & 3, e = c & 7;
    int lane = lhi * 16 + l15;
    kptF[(((((b * MITER + mi) * 4 + mf) * 2 + ks)) * 64 + lane) * 8 + e] = (_Float16)s;
  }
}

// ---------------- pass A: colsum[b][m] = sum_n exp(scores[b][n][m]) --------
// 8 waves x 32 rows; full kptF batch (72KB) staged once; no loop barriers.
// launch_bounds(512,4): 16 waves/CU min -> VGPR cap 128 (was 52: the compiler
// was rationing registers so hard each MFMA serialized on its own ds_read).
// bfr register double-bank: prefetch body mi+1's fragments during body mi.
__global__ __launch_bounds__(512, 4) void colsum_kernel(
    const float* __restrict__ Q, const _Float16* __restrict__ kptF,
    float* __restrict__ colsum) {
  __shared__ float cs[MP];
  __shared__ char stg[MITER * 8 * 1024];  // 72KB
  int b = blockIdx.y;
  int n0 = blockIdx.x * 256;
  int tid = threadIdx.x;
  int wv = tid >> 6;
  int lane = tid & 63;
  int l15 = lane & 15, lhi = lane >> 4;

  for (int i = tid; i < MP; i += 512) cs[i] = 0.f;

  const _Float16* kb = kptF + b * MITER * 8 * 512;
#pragma unroll
  for (int j = 0; j < 9; ++j) {
    int q = wv * 9 + j;
    gload16(kb + q * 512 + lane * 8, stg + q * 1024);
  }

  const float* Qb = Q + b * CC * HWN;
  int nrow = n0 + wv * 32 + l15;
  half8 afrag[2][2];
#pragma unroll
  for (int nf = 0; nf < 2; ++nf)
#pragma unroll
    for (int ks = 0; ks < 2; ++ks)
#pragma unroll
      for (int e = 0; e < 8; ++e)
        afrag[nf][ks][e] = (_Float16)Qb[(ks * 32 + lhi * 8 + e) * HWN + nrow + nf * 16];

  __syncthreads();  // stage + cs-init visible

  floatx4 zero = {0.f, 0.f, 0.f, 0.f};
  half8 bfr[2][4][2];  // register double-bank
#pragma unroll
  for (int mf = 0; mf < 4; ++mf)
#pragma unroll
    for (int ks = 0; ks < 2; ++ks)
      bfr[0][mf][ks] = *(const half8*)(stg + ((0 * 4 + mf) * 2 + ks) * 1024 + lane * 16);

#pragma unroll
  for (int mi = 0; mi < MITER; ++mi) {
    // prefetch next body's fragments (lands under this body's MFMA+exp)
    if (mi + 1 < MITER) {
#pragma unroll
      for (int mf = 0; mf < 4; ++mf)
#pragma unroll
        for (int ks = 0; ks < 2; ++ks)
          bfr[(mi + 1) & 1][mf][ks] =
              *(const half8*)(stg + (((mi + 1) * 4 + mf) * 2 + ks) * 1024 + lane * 16);
    }
    floatx4 sacc[2][4];
#pragma unroll
    for (int nf = 0; nf < 2; ++nf)
#pragma unroll
      for (int mf = 0; mf < 4; ++mf) sacc[nf][mf] = zero;
    __builtin_amdgcn_s_setprio(1);
#pragma unroll
    for (int ks = 0; ks < 2; ++ks)
#pragma unroll
      for (int nf = 0; nf < 2; ++nf)
#pragma unroll
        for (int mf = 0; mf < 4; ++mf)
          sacc[nf][mf] = __builtin_amdgcn_mfma_f32_16x16x32_f16(
              afrag[nf][ks], bfr[mi & 1][mf][ks], sacc[nf][mf], 0, 0, 0);
    __builtin_amdgcn_s_setprio(0);
#pragma unroll
    for (int mf = 0; mf < 4; ++mf) {
      float s = 0.f;
#pragma unroll
      for (int nf = 0; nf < 2; ++nf)
#pragma unroll
        for (int r = 0; r < 4; ++r)
          s += __expf(sacc[nf][mf][r]);
      s += __shfl_xor(s, 16);
      s += __shfl_xor(s, 32);
      if (lane < 16) atomicAdd(&cs[mi * 64 + l15 * 4 + mf], s);
    }
  }
  __syncthreads();
  for (int i = tid; i < MP; i += 512) atomicAdd(&colsum[b * MP + i], cs[i]);
}

// ---------------- W' = Vp/colsum * 2^16 (f16, frag-order) ------------------
__global__ __launch_bounds__(256) void wprep_kernel(
    const float* __restrict__ vp, const float* __restrict__ colsum,
    _Float16* __restrict__ wqF) {
  int t = blockIdx.x * 256 + threadIdx.x;
  int m = t % MP;
  int c = (t / MP) % CC;
  int b = t / (CC * MP);
  float w = vp[t] / colsum[b * MP + m] * SCALE_W;
  int cf = c >> 4, l15 = c & 15;
  int mi = m >> 6, mloc = m & 63;
  int ks = mloc >> 5, lhi = (mloc >> 3) & 3, e = mloc & 7;
  int lane = lhi * 16 + l15;
  wqF[((((b * MITER + mi) * 4 + cf) * 2 + ks) * 64 + lane) * 8 + e] = (_Float16)w;
}

// ---------------- pass B: out[b][c][n] = sum_m W'[c][m]*E[n][m] * 2^-16 ----
// 4 waves x 32 rows; 3-slot ring, counted vmcnt; E single-buffered per wave.
// launch_bounds(256,2): 8 waves/CU min -> VGPR cap 256 (was 88) so the body's
// 20 batched ds_reads can pipeline instead of serializing.
__global__ __launch_bounds__(256, 2) void attn_main_kernel(
    const float* __restrict__ Q, const _Float16* __restrict__ kptF,
    const _Float16* __restrict__ wqF, float* __restrict__ out) {
  __shared__ char lds[3 * 16384 + 4 * 4096];  // 64KB exactly
  char* stg = lds;
  int b = blockIdx.y;
  int n0 = blockIdx.x * 128;
  int tid = threadIdx.x;
  int wv = tid >> 6;
  int lane = tid & 63;
  int l15 = lane & 15, lhi = lane >> 4;
  char* eb = lds + 49152 + wv * 4096;

  const _Float16* kb = kptF + b * MITER * 8 * 512;
  const _Float16* wb = wqF + b * MITER * 8 * 512;

#define STAGE_A(tt, ss)                                                        \
  {                                                                            \
    int q0_ = wv * 4;                                                          \
    _Pragma("unroll") for (int j_ = 0; j_ < 4; ++j_) {                         \
      int q_ = q0_ + j_;                                                       \
      const _Float16* sp_ = (q_ < 8 ? kb + (tt) * 4096 + q_ * 512              \
                                    : wb + (tt) * 4096 + (q_ - 8) * 512) +     \
                            lane * 8;                                          \
      gload16(sp_, stg + (ss) * 16384 + q_ * 1024);                            \
    }                                                                          \
  }

  STAGE_A(0, 0);
  STAGE_A(1, 1);

  const float* Qb = Q + b * CC * HWN;
  int nrow = n0 + wv * 32 + l15;
  half8 afrag[2][2];
#pragma unroll
  for (int nf = 0; nf < 2; ++nf)
#pragma unroll
    for (int ks = 0; ks < 2; ++ks)
#pragma unroll
      for (int e = 0; e < 8; ++e)
        afrag[nf][ks][e] = (_Float16)Qb[(ks * 32 + lhi * 8 + e) * HWN + nrow + nf * 16];

  floatx4 zero = {0.f, 0.f, 0.f, 0.f};
  floatx4 oacc[4][2];
#pragma unroll
  for (int cf = 0; cf < 4; ++cf)
#pragma unroll
    for (int nf = 0; nf < 2; ++nf) oacc[cf][nf] = zero;

  WAITCNT_VM(4);
  __builtin_amdgcn_sched_barrier(0);
  __builtin_amdgcn_s_barrier();

#pragma unroll
  for (int mi = 0; mi < MITER; ++mi) {
    const int sc = mi % 3;
    const int spv = (mi + 2) % 3;

    if (mi >= 1) {
      if (mi <= 7) { WAITCNT_VM(4); } else { WAITCNT_VM(0); }
      __builtin_amdgcn_sched_barrier(0);
      __builtin_amdgcn_s_barrier();
    }

    half8 bfr[4][2];
#pragma unroll
    for (int mf = 0; mf < 4; ++mf)
#pragma unroll
      for (int ks = 0; ks < 2; ++ks)
        bfr[mf][ks] = *(const half8*)(stg + sc * 16384 + (mf * 2 + ks) * 1024 + lane * 16);
    half8 wfr[4][2];
    half8 ef[2][2];
    if (mi >= 1) {
#pragma unroll
      for (int cf = 0; cf < 4; ++cf)
#pragma unroll
        for (int ks = 0; ks < 2; ++ks)
          wfr[cf][ks] = *(const half8*)(stg + spv * 16384 + 8192 + (cf * 2 + ks) * 1024 + lane * 16);
#pragma unroll
      for (int nf = 0; nf < 2; ++nf)
#pragma unroll
        for (int ks = 0; ks < 2; ++ks) {
          int nl = nf * 16 + l15;
          int slot = (ks * 4 + lhi) ^ (nl & 7);
          ef[nf][ks] = *(const half8*)(eb + nl * 128 + (slot << 4));
        }
    }

    WAITCNT_LGKM0;
    __builtin_amdgcn_sched_barrier(0);
    __builtin_amdgcn_s_barrier();

    if (mi + 2 < MITER) STAGE_A(mi + 2, spv);

    floatx4 sacc[2][4];
#pragma unroll
    for (int nf = 0; nf < 2; ++nf)
#pragma unroll
      for (int mf = 0; mf < 4; ++mf) sacc[nf][mf] = zero;
    __builtin_amdgcn_s_setprio(1);
#pragma unroll
    for (int ks = 0; ks < 2; ++ks)
#pragma unroll
      for (int nf = 0; nf < 2; ++nf)
#pragma unroll
        for (int mf = 0; mf < 4; ++mf)
          sacc[nf][mf] = __builtin_amdgcn_mfma_f32_16x16x32_f16(
              afrag[nf][ks], bfr[mf][ks], sacc[nf][mf], 0, 0, 0);
    if (mi >= 1) {
#pragma unroll
      for (int ks = 0; ks < 2; ++ks)
#pragma unroll
        for (int cf = 0; cf < 4; ++cf)
#pragma unroll
          for (int nf = 0; nf < 2; ++nf)
            oacc[cf][nf] = __builtin_amdgcn_mfma_f32_16x16x32_f16(
                wfr[cf][ks], ef[nf][ks], oacc[cf][nf], 0, 0, 0);
    }
    __builtin_amdgcn_s_setprio(0);

#pragma unroll
    for (int nf = 0; nf < 2; ++nf)
#pragma unroll
      for (int r = 0; r < 4; ++r) {
        int nl = nf * 16 + lhi * 4 + r;
        half4 h;
#pragma unroll
        for (int mf = 0; mf < 4; ++mf) h[mf] = (_Float16)__expf(sacc[nf][mf][r]);
        int byte = nl * 128 + ((((l15 >> 1) ^ (nl & 7))) << 4) + ((l15 & 1) << 3);
        *(half4*)(eb + byte) = h;
      }
  }

  {
    half8 wfr[4][2];
#pragma unroll
    for (int cf = 0; cf < 4; ++cf)
#pragma unroll
      for (int ks = 0; ks < 2; ++ks)
        wfr[cf][ks] = *(const half8*)(stg + 2 * 16384 + 8192 + (cf * 2 + ks) * 1024 + lane * 16);
    half8 ef[2][2];
#pragma unroll
    for (int nf = 0; nf < 2; ++nf)
#pragma unroll
      for (int ks = 0; ks < 2; ++ks) {
        int nl = nf * 16 + l15;
        int slot = (ks * 4 + lhi) ^ (nl & 7);
        ef[nf][ks] = *(const half8*)(eb + nl * 128 + (slot << 4));
      }
    __builtin_amdgcn_s_setprio(1);
#pragma unroll
    for (int ks = 0; ks < 2; ++ks)
#pragma unroll
      for (int cf = 0; cf < 4; ++cf)
#pragma unroll
        for (int nf = 0; nf < 2; ++nf)
          oacc[cf][nf] = __builtin_amdgcn_mfma_f32_16x16x32_f16(
              wfr[cf][ks], ef[nf][ks], oacc[cf][nf], 0, 0, 0);
    __builtin_amdgcn_s_setprio(0);
  }

  float* ob = out + b * CC * HWN;
#pragma unroll
  for (int cf = 0; cf < 4; ++cf)
#pragma unroll
    for (int nf = 0; nf < 2; ++nf)
#pragma unroll
      for (int r = 0; r < 4; ++r) {
        int c = cf * 16 + lhi * 4 + r;
        int n = n0 + wv * 32 + nf * 16 + l15;
        ob[c * HWN + n] = oacc[cf][nf][r] * INV_SCALE;
      }
}

extern "C" void kernel_launch(void* const* d_in, const int* in_sizes, int n_in,
                              void* d_out, int out_size, void* d_ws, size_t ws_size,
                              hipStream_t stream) {
  const float* K = (const float*)d_in[0];
  const float* Q = (const float*)d_in[1];
  const float* V = (const float*)d_in[2];
  float* out = (float*)d_out;
  char* ws = (char*)d_ws;
  _Float16* kptF  = (_Float16*)(ws);                          // 294912 B
  float*    vp    = (float*)(ws + 294912);                    // 589824 B
  _Float16* wqF   = (_Float16*)(ws + 294912 + 589824);        // 294912 B
  float*    colsum = (float*)(ws + 294912 + 589824 + 294912); // 9216 B

  hipMemsetAsync(colsum, 0, BB * MP * sizeof(float), stream);
  pool_kernel<<<(2 * BB * CC * MP) / 256, 256, 0, stream>>>(K, V, kptF, vp);
  colsum_kernel<<<dim3(HWN / 256, BB), 512, 0, stream>>>(Q, kptF, colsum);
  wprep_kernel<<<(BB * CC * MP) / 256, 256, 0, stream>>>(vp, colsum, wqF);
  attn_main_kernel<<<dim3(HWN / 128, BB), 256, 0, stream>>>(Q, kptF, wqF, out);
}